// Round 5
// baseline (753.388 us; speedup 1.0000x reference)
//
#include <hip/hip_runtime.h>
#include <hip/hip_bf16.h>

// ---- static problem geometry (from reference: IMAGE_SIZES // 14) ----
// merged rows: 3025 2200 1760 1260 2916 2200 1024 2475 -> 16860 (pad to 16896 = 66*256)
#define MTOK  16860
#define NOUT  1024
#define KDIM  4096
#define NBM   66       // M tiles of 256
#define KTILES 64      // KDIM / 64

__device__ __constant__ int c_mend[8] = {3025,5225,6985,8245,11161,13361,14385,16860};
__device__ __constant__ int c_moff[8] = {0,3025,5225,6985,8245,11161,13361,14385};
__device__ __constant__ int c_foff[8] = {0,12100,20900,27940,32980,44644,53444,57540};
__device__ __constant__ int c_wp[8]   = {110,110,64,90,108,80,64,110};

typedef __attribute__((ext_vector_type(8))) short          bf16x8;
typedef __attribute__((ext_vector_type(4))) float          f32x4;

#define VMCNT(n) asm volatile("s_waitcnt vmcnt(" #n ")" ::: "memory")
#define LGKM0()  asm volatile("s_waitcnt lgkmcnt(0)" ::: "memory")
#define BARR()   __builtin_amdgcn_s_barrier()
#define SCHED0() __builtin_amdgcn_sched_barrier(0)

__device__ __forceinline__ unsigned short f2bf(float f) {
    unsigned int u = __float_as_uint(f);
    u += 0x7FFFu + ((u >> 16) & 1u);   // round-to-nearest-even
    return (unsigned short)(u >> 16);
}

// packed fp32x2 -> bf16x2 (RNE hardware cvt; same rounding as f2bf)
__device__ __forceinline__ unsigned int pkbf(float lo, float hi) {
    unsigned int r;
    asm("v_cvt_pk_bf16_f32 %0, %1, %2" : "=v"(r) : "v"(lo), "v"(hi));
    return r;
}

__device__ __forceinline__ void async_copy16(const void* g, void* l) {
    __builtin_amdgcn_global_load_lds(
        (const __attribute__((address_space(1))) void*)g,
        (__attribute__((address_space(3))) void*)l, 16, 0, 0);
}

// ---- kernel 1: weight fp32 -> bf16 with K-permutation (16 MB read, ~5 us) ----
// kappa' = c*1024 + d  (c = 2*ki+kj): Wb[n][c*1024+d] = W[n][4d+c].
__global__ __launch_bounds__(256) void cast_w_perm(const float* __restrict__ W,
                                                   unsigned short* __restrict__ Wb) {
    int g = blockIdx.x * 256 + threadIdx.x;   // 0 .. 1024*1024-1
    int n = g >> 10, d = g & 1023;
    float4 v = *(const float4*)(W + (size_t)n * 4096 + d * 4);
    unsigned short* o = Wb + (size_t)n * 4096 + d;
    o[0]    = f2bf(v.x);
    o[1024] = f2bf(v.y);
    o[2048] = f2bf(v.z);
    o[3072] = f2bf(v.w);
}

// ---- kernel 2: fused merge+cast+GEMM, phase-split schedule (T2+T3+T4+T5) ----
// Tile 256x128, BK=64, 512 threads = 8 waves (4M x 2N, 64x64 each).
// LDS: lA 2x32K + lB 2x16K = 96 KiB -> 1 block/CU.
// Per dbuf iteration (tiles 2j->buf0, 2j+1->buf1): 4 phases, each
//   {ds_read 12 frags | one stage op ; BARRIER ; 16 MFMA (setprio) ;
//    counted vmcnt ; lgkmcnt(0) ; BARRIER}
// VMEM queue invariant (FIFO): [B(t+1)*2, A(t+2)*8]; vmcnt(8) proves B landed
// (before the barrier preceding its first read -> cross-wave safe); vmcnt(2)
// proves the private A regs arrived for writeA. Never drains to 0 mid-loop.
__global__ __launch_bounds__(512, 2) void gemm8(const float* __restrict__ F,
                                                const unsigned short* __restrict__ B,
                                                float* __restrict__ C) {
    __shared__ unsigned short lA[2][256 * 64];   // 2 x 32 KiB
    __shared__ unsigned short lB[2][128 * 64];   // 2 x 16 KiB

    // bijective XCD swizzle: 528 = 8 XCDs * 66 chunks; 8 bn-siblings share an XCD
    const int orig    = blockIdx.y * 8 + blockIdx.x;
    const int logical = (orig & 7) * NBM + (orig >> 3);
    const int bn = logical & 7;          // 0..7
    const int bm = logical >> 3;         // 0..65

    const int tid  = threadIdx.x;
    const int wave = tid >> 6, lane = tid & 63;
    const int wmOff = (wave >> 1) * 64;  // 0,64,128,192
    const int wnOff = (wave & 1) * 64;   // 0,64

    // staging constants: 8 threads per row (16B bf16 chunks), 64 rows per group
    const int srow = tid >> 3;           // 0..63
    const int sp   = tid & 7;            // 0..7
    const int sw   = srow & 7;           // row-XOR swizzle key
    const int bssw = (sp ^ sw) * 8;      // pre-swizzled global src elem offset
    const int sdst = srow * 64 + sp * 8; // linear LDS dest (lane-ordered)

    // per-thread A gather metadata for merged rows i*64 + srow
    int fbase[4], fwp[4];
#pragma unroll
    for (int i = 0; i < 4; ++i) {
        int t = bm * 256 + i * 64 + srow;
        if (t >= MTOK) t = 0;            // pad rows: read valid garbage, store masked
        int im = 0;
        while (t >= c_mend[im]) im++;
        int rr  = t - c_moff[im];
        int wp  = c_wp[im];
        int wp2 = wp >> 1;
        int ii = rr / wp2, jj = rr - ii * wp2;
        fbase[i] = c_foff[im] + 2 * ii * wp + 2 * jj;
        fwp[i]   = wp;
    }
    const unsigned short* Bb = B + (size_t)(bn * 128) * KDIM;

    // A: 8 fp32 dwordx4 loads into regs (4 rows x 8 floats)
    auto issueA = [&](int kt, float4 (&rg)[8]) {
        const int k0 = kt * 64;
        const int c  = k0 >> 10;
        const int dA = (k0 & 1023) + sp * 8;
#pragma unroll
        for (int i = 0; i < 4; ++i) {
            int fr = fbase[i] + ((c & 2) ? fwp[i] : 0) + (c & 1);
            const float* src = F + (((size_t)fr) << 10) + dA;
            rg[2 * i]     = *(const float4*)(src);
            rg[2 * i + 1] = *(const float4*)(src + 4);
        }
    };
    // cvt + swizzled LDS write: logical chunk sp stored at physical chunk sp^(row&7)
    auto writeA = [&](float4 (&rg)[8], int buf) {
#pragma unroll
        for (int i = 0; i < 4; ++i) {
            float4 x = rg[2 * i], y = rg[2 * i + 1];
            uint4 v;
            v.x = pkbf(x.x, x.y); v.y = pkbf(x.z, x.w);
            v.z = pkbf(y.x, y.y); v.w = pkbf(y.z, y.w);
            *(uint4*)&lA[buf][(i * 64 + srow) * 64 + ((sp ^ sw) * 8)] = v;
        }
    };
    // B: 2 global_load_lds (pre-swizzled source, linear lane-ordered dest)
    auto issueB = [&](int kt, int buf) {
        const int k0 = kt * 64;
#pragma unroll
        for (int i = 0; i < 2; ++i)
            async_copy16(Bb + (size_t)(i * 64 + srow) * KDIM + k0 + bssw,
                         &lB[buf][i * 4096 + sdst]);
    };

    f32x4 acc[4][4];
#pragma unroll
    for (int a = 0; a < 4; ++a)
#pragma unroll
        for (int b = 0; b < 4; ++b) acc[a][b] = (f32x4){0.f, 0.f, 0.f, 0.f};

    const int mrow = lane & 15;
    const int q8   = (lane >> 4) * 8;
    const int rsw  = (mrow & 7) * 8;     // ds_read swizzle (row&7 == mrow&7)

    bf16x8 af[2][2], bfr[4][2];
    auto readFrags = [&](int buf, int h) {
#pragma unroll
        for (int ks = 0; ks < 2; ++ks) {
            const int col = (ks * 32 + q8) ^ rsw;
#pragma unroll
            for (int ai = 0; ai < 2; ++ai)
                af[ai][ks] = *(const bf16x8*)&lA[buf][(wmOff + (2 * h + ai) * 16 + mrow) * 64 + col];
#pragma unroll
            for (int b = 0; b < 4; ++b)
                bfr[b][ks] = *(const bf16x8*)&lB[buf][(wnOff + b * 16 + mrow) * 64 + col];
        }
    };
    auto mfmaHalf = [&](int h) {
        __builtin_amdgcn_s_setprio(1);
#pragma unroll
        for (int ai = 0; ai < 2; ++ai)
#pragma unroll
            for (int b = 0; b < 4; ++b)
#pragma unroll
                for (int ks = 0; ks < 2; ++ks)
                    acc[2 * h + ai][b] = __builtin_amdgcn_mfma_f32_16x16x32_bf16(
                        af[ai][ks], bfr[b][ks], acc[2 * h + ai][b], 0, 0, 0);
        __builtin_amdgcn_s_setprio(0);
    };

    float4 rE[8], rO[8];

    // ---- prologue: buf0 = tile 0 ready; queue = [A1*8] ----
    issueA(0, rE);                       // [A0*8]
    issueB(0, 0);                        // [A0*8, B0*2]
    VMCNT(2);                            // A0 arrived
    writeA(rE, 0);
    issueA(1, rO);                       // [B0*2, A1*8]
    VMCNT(8);                            // B0 landed
    LGKM0();
    SCHED0();
    BARR();                              // buf0 complete for all waves

    // ---- main loop: iters j=0..30 consume tiles 2j,2j+1; stage 2j+1..2j+3 ----
#pragma unroll 1
    for (int j = 0; j < 31; ++j) {
        // p0: buf0 h0            queue in: [A(2j+1)*8]
        readFrags(0, 0);
        issueB(2 * j + 1, 1);            // [A*8, B*2]
        BARR(); SCHED0();
        mfmaHalf(0);
        SCHED0(); LGKM0(); BARR();
        // p1: buf0 h1
        VMCNT(2);                        // A(2j+1) arrived (leaves B(2j+1)*2)
        writeA(rO, 1);
        readFrags(0, 1);
        issueA(2 * j + 2, rE);           // [B*2, A(2j+2)*8]
        BARR(); SCHED0();
        mfmaHalf(1);
        SCHED0();
        VMCNT(8);                        // B(2j+1) landed
        LGKM0(); BARR();                 // buf1 complete; buf0 free
        // p2: buf1 h0
        readFrags(1, 0);
        issueB(2 * j + 2, 0);            // [A*8, B*2]
        BARR(); SCHED0();
        mfmaHalf(0);
        SCHED0(); LGKM0(); BARR();
        // p3: buf1 h1
        VMCNT(2);                        // A(2j+2) arrived
        writeA(rE, 0);
        readFrags(1, 1);
        issueA(2 * j + 3, rO);           // [B*2, A(2j+3)*8]
        BARR(); SCHED0();
        mfmaHalf(1);
        SCHED0();
        VMCNT(8);                        // B(2j+2) landed
        LGKM0(); BARR();                 // buf0 complete; buf1 free
    }

    // ---- peeled last iter: tiles 62 (buf0), 63 (buf1); rO = A63 in flight ----
    readFrags(0, 0);
    issueB(63, 1);                       // [A63*8, B63*2]
    BARR(); SCHED0();
    mfmaHalf(0);
    SCHED0(); LGKM0(); BARR();

    VMCNT(2);                            // A63 arrived
    writeA(rO, 1);
    readFrags(0, 1);
    BARR(); SCHED0();
    mfmaHalf(1);
    SCHED0();
    VMCNT(0);                            // B63 landed
    LGKM0(); BARR();                     // buf1 complete

    readFrags(1, 0);
    BARR(); SCHED0();
    mfmaHalf(0);
    SCHED0(); BARR();

    readFrags(1, 1);
    mfmaHalf(1);

    // ---- epilogue: C/D layout col=lane&15, row=(lane>>4)*4+reg ----
    const int col   = lane & 15;
    const int rquad = (lane >> 4) * 4;
#pragma unroll
    for (int a = 0; a < 4; ++a) {
        int gm0 = bm * 256 + wmOff + a * 16 + rquad;
#pragma unroll
        for (int b = 0; b < 4; ++b) {
            int gn = bn * 128 + wnOff + b * 16 + col;
#pragma unroll
            for (int rg = 0; rg < 4; ++rg) {
                int gm = gm0 + rg;
                if (gm < MTOK) C[(size_t)gm * NOUT + gn] = acc[a][b][rg];
            }
        }
    }
}

// ---- fallback (ws too small): exact fp32, slow but correct ----
__global__ __launch_bounds__(256) void naive_fb(const float* __restrict__ feats,
                                                const float* __restrict__ W,
                                                float* __restrict__ out) {
    int t = blockIdx.x;
    int o = blockIdx.y * 256 + threadIdx.x;
    int im = 0;
    while (t >= c_mend[im]) im++;
    int r = t - c_moff[im];
    int wp = c_wp[im], wp2 = wp >> 1;
    int i = r / wp2, j = r - i * wp2;
    const float* f00 = feats + (size_t)(c_foff[im] + (2*i)*wp + 2*j) * 1024;
    const float* f10 = f00 + (size_t)wp * 1024;
    const float* w = W + (size_t)o * 4096;
    float s = 0.f;
    for (int d = 0; d < 1024; ++d)
        s += f00[d] * w[d*4] + f00[d+1024] * w[d*4+1] + f10[d] * w[d*4+2] + f10[d+1024] * w[d*4+3];
    out[(size_t)t * 1024 + o] = s;
}

extern "C" void kernel_launch(void* const* d_in, const int* in_sizes, int n_in,
                              void* d_out, int out_size, void* d_ws, size_t ws_size,
                              hipStream_t stream) {
    const float* feats = (const float*)d_in[0];   // [67440, 1024] fp32
    const float* W     = (const float*)d_in[1];   // [1024, 4096] fp32
    float* out         = (float*)d_out;           // [16860, 1024] fp32

    const size_t need = (size_t)NOUT * KDIM * sizeof(unsigned short);  // 8 MB
    if (ws_size >= need) {
        unsigned short* Wb = (unsigned short*)d_ws;   // [1024, 4096] bf16 (K-permuted)
        cast_w_perm<<<dim3(4096), 256, 0, stream>>>(W, Wb);
        gemm8<<<dim3(8, NBM), 512, 0, stream>>>(feats, Wb, out);
    } else {
        naive_fb<<<dim3(MTOK, 4), 256, 0, stream>>>(feats, W, out);
    }
}